// Round 4
// baseline (492.989 us; speedup 1.0000x reference)
//
#include <hip/hip_runtime.h>
#include <hip/hip_bf16.h>
#include <stdint.h>
#include <stddef.h>

// Problem constants
#define D_DIM 2048
#define H_HEADS 16
#define KV_HEADS 4
#define HEAD_DIM 128
#define SEQ_L 2048
#define BATCH 2
#define NTOK 4096      // BATCH*SEQ_L
#define NQK 2560       // D + KV_HEADS*HEAD_DIM   (Q + K only; V handled separately)

typedef __attribute__((ext_vector_type(4))) float f32x4;
typedef __attribute__((ext_vector_type(8))) short bf16x8;

__device__ __forceinline__ unsigned short f2bf(float f) {
  unsigned int u = __float_as_uint(f);
  unsigned int r = u + 0x7fffu + ((u >> 16) & 1u);   // RTNE
  return (unsigned short)(r >> 16);
}
__device__ __forceinline__ float bf2f(unsigned short s) {
  return __uint_as_float(((unsigned int)s) << 16);
}

__device__ __forceinline__ void async_copy16(const void* g, void* l) {
  __builtin_amdgcn_global_load_lds(
      (__attribute__((address_space(1))) void*)(g),
      (__attribute__((address_space(3))) void*)(l),
      16, 0, 0);
}

// ---------------- fp32 -> bf16 cast ----------------
__global__ __launch_bounds__(256) void cast_kernel(const float* __restrict__ src,
                                                   unsigned short* __restrict__ dst, int n) {
  int idx = blockIdx.x * blockDim.x + threadIdx.x;
  int stride = gridDim.x * blockDim.x;
  for (int i = idx * 4; i < n; i += stride * 4) {
    float4 v = *reinterpret_cast<const float4*>(src + i);
    ushort4 o;
    o.x = f2bf(v.x); o.y = f2bf(v.y); o.z = f2bf(v.z); o.w = f2bf(v.w);
    *reinterpret_cast<ushort4*>(dst + i) = o;
  }
}

// ---------------- RoPE table ----------------
__global__ __launch_bounds__(256) void rope_table_kernel(float* __restrict__ cosT,
                                                         float* __restrict__ sinT) {
  int i = blockIdx.x * blockDim.x + threadIdx.x;  // l*64 + p
  if (i >= SEQ_L * 64) return;
  int p = i & 63;
  float l = (float)(i >> 6);
  float inv = powf(10000.0f, -(float)p / 64.0f);
  float ang = l * inv;
  cosT[i] = cosf(ang);
  sinT[i] = sinf(ang);
}

// ---------------- GEMM: C[M,N] = A[M,K] * B[N,K]^T  (bf16 in, OutT out) ----------------
__device__ __forceinline__ void store_out(unsigned short* p, float v) { *p = f2bf(v); }
__device__ __forceinline__ void store_out(float* p, float v) { *p = v; }

template <typename OutT>
__global__ __launch_bounds__(256) void gemm_bt_kernel(const unsigned short* __restrict__ A,
                                                      const unsigned short* __restrict__ B,
                                                      OutT* __restrict__ C,
                                                      int M, int N, int K) {
  __shared__ unsigned short Alds[128 * 32];
  __shared__ unsigned short Blds[128 * 32];
  const int tid = threadIdx.x;
  const int wave = tid >> 6;
  const int lane = tid & 63;
  const int l15 = lane & 15;
  const int l4 = lane >> 4;
  const int m0 = blockIdx.x * 128;
  const int n0 = blockIdx.y * 128;
  const int wm = (wave >> 1) * 64;
  const int wn = (wave & 1) * 64;

  f32x4 acc[4][4] = {};

  const int soff0 = wave * 1024 + lane * 16;  // bytes within 8KB tile

  for (int kt = 0; kt < K; kt += 32) {
#pragma unroll
    for (int inst = 0; inst < 2; ++inst) {
      int off = soff0 + inst * 4096;
      int row = off >> 6;    // 64 bytes (32 bf16) per LDS row
      int colb = off & 63;
      const char* ga = (const char*)(A + (size_t)(m0 + row) * K + kt) + colb;
      async_copy16(ga, (char*)Alds + off);
      const char* gb = (const char*)(B + (size_t)(n0 + row) * K + kt) + colb;
      async_copy16(gb, (char*)Blds + off);
    }
    __syncthreads();
    bf16x8 af[4], bfr[4];
#pragma unroll
    for (int i = 0; i < 4; ++i)
      af[i] = *reinterpret_cast<const bf16x8*>(Alds + (wm + i * 16 + l15) * 32 + l4 * 8);
#pragma unroll
    for (int j = 0; j < 4; ++j)
      bfr[j] = *reinterpret_cast<const bf16x8*>(Blds + (wn + j * 16 + l15) * 32 + l4 * 8);
#pragma unroll
    for (int i = 0; i < 4; ++i)
#pragma unroll
      for (int j = 0; j < 4; ++j)
        acc[i][j] = __builtin_amdgcn_mfma_f32_16x16x32_bf16(af[i], bfr[j], acc[i][j], 0, 0, 0);
    __syncthreads();
  }

#pragma unroll
  for (int i = 0; i < 4; ++i)
#pragma unroll
    for (int j = 0; j < 4; ++j) {
      int col = n0 + wn + j * 16 + l15;
#pragma unroll
      for (int r = 0; r < 4; ++r) {
        int row = m0 + wm + i * 16 + l4 * 4 + r;
        store_out(C + (size_t)row * N + col, acc[i][j][r]);
      }
    }
}

// ---------------- RMSNorm + RoPE (in-place on QK buffer, stride NQK) ----------------
__global__ __launch_bounds__(256) void norm_rope_kernel(unsigned short* __restrict__ qk,
                                                        const float* __restrict__ qw,
                                                        const float* __restrict__ kw,
                                                        const float* __restrict__ cosT,
                                                        const float* __restrict__ sinT) {
  int wid = (blockIdx.x * blockDim.x + threadIdx.x) >> 6;  // global wave id
  int lane = threadIdx.x & 63;
  unsigned short* rowp;
  const float* w;
  int m;
  if (wid < NTOK * H_HEADS) {
    m = wid >> 4;
    int hh = wid & 15;
    rowp = qk + (size_t)m * NQK + hh * HEAD_DIM;
    w = qw;
  } else {
    int r2 = wid - NTOK * H_HEADS;
    m = r2 >> 2;
    int kvh = r2 & 3;
    rowp = qk + (size_t)m * NQK + D_DIM + kvh * HEAD_DIM;
    w = kw;
  }
  int l = m & (SEQ_L - 1);
  unsigned int pair = *reinterpret_cast<const unsigned int*>(rowp + lane * 2);
  float e = bf2f((unsigned short)(pair & 0xffffu));
  float o = bf2f((unsigned short)(pair >> 16));
  float ss = e * e + o * o;
#pragma unroll
  for (int off = 1; off < 64; off <<= 1) ss += __shfl_xor(ss, off);
  float rsn = rsqrtf(ss * (1.0f / 128.0f) + 1e-6f);
  float we = w[lane * 2], wo_ = w[lane * 2 + 1];
  float c = cosT[l * 64 + lane], s = sinT[l * 64 + lane];
  float xe = e * rsn * we, xo = o * rsn * wo_;
  float re = xe * c - xo * s;
  float ro = xe * s + xo * c;
  unsigned int opack = (unsigned int)f2bf(re) | ((unsigned int)f2bf(ro) << 16);
  *reinterpret_cast<unsigned int*>(rowp + lane * 2) = opack;
}

// ---------------- Flash attention (R1-verified 16x16 structure) ----------------
// Block: 256 threads = 4 waves. Each block: one (b,h), 64 q rows; each wave 16 q rows.
// Inputs adapted: qk has stride NQK (K at +D_DIM); V comes pre-transposed from vt.
__global__ __launch_bounds__(256) void attn_kernel(const unsigned short* __restrict__ qk,
                                                   const unsigned short* __restrict__ vt,
                                                   unsigned short* __restrict__ obuf) {
  __shared__ unsigned short Klds[64 * 136];      // keys x HD, pad 128->136
  __shared__ unsigned short Vt[128 * 72];        // d x keys, pad 64->72
  __shared__ unsigned short Plds[4][16 * 72];    // per-wave P tile, pad 64->72

  const int tid = threadIdx.x;
  const int wave = tid >> 6, lane = tid & 63;
  const int l15 = lane & 15, l4 = lane >> 4;
  const int q0 = blockIdx.x * 64;
  const int bh = blockIdx.y;
  const int b = bh >> 4, h = bh & 15;
  const int kvh = h >> 2;

  const size_t base = (size_t)b * SEQ_L * NQK;
  const unsigned short* Kg = qk + base + D_DIM + kvh * HEAD_DIM;
  const unsigned short* Vg = vt + (size_t)(kvh * HEAD_DIM) * NTOK + b * SEQ_L;

  // Q fragments: wave's rows q0+wave*16+l15
  bf16x8 qf[4];
  {
    const unsigned short* qrow = qk + base + (size_t)(q0 + wave * 16 + l15) * NQK + h * HEAD_DIM;
#pragma unroll
    for (int kk = 0; kk < 4; ++kk)
      qf[kk] = *reinterpret_cast<const bf16x8*>(qrow + kk * 32 + l4 * 8);
  }

  f32x4 accO[8];
#pragma unroll
  for (int jd = 0; jd < 8; ++jd) accO[jd] = f32x4{0.f, 0.f, 0.f, 0.f};
  float mrun[4], lrun[4];
#pragma unroll
  for (int r = 0; r < 4; ++r) { mrun[r] = -1e30f; lrun[r] = 0.0f; }

  const int nkt = q0 / 64;  // inclusive last kv-tile
  const float scale = 0.08838834764831845f;  // 1/sqrt(128)

  for (int kt = 0; kt <= nkt; ++kt) {
    // stage K tile (coalesced, padded rows)
#pragma unroll
    for (int i = 0; i < 4; ++i) {
      int c = tid + i * 256;           // 1024 chunks of 16B
      int row = c >> 4, sub = c & 15;
      bf16x8 v = *reinterpret_cast<const bf16x8*>(Kg + (size_t)(kt * 64 + row) * NQK + sub * 8);
      *reinterpret_cast<bf16x8*>(&Klds[row * 136 + sub * 8]) = v;
    }
    // stage Vt[d][key] from VT global rows (already transposed): straight row copy
#pragma unroll
    for (int i = 0; i < 4; ++i) {
      int task = tid + i * 256;        // 1024 tasks: d = task>>3, sub = task&7
      int d = task >> 3, sub = task & 7;
      bf16x8 v = *reinterpret_cast<const bf16x8*>(Vg + (size_t)d * NTOK + kt * 64 + sub * 8);
      *reinterpret_cast<bf16x8*>(&Vt[d * 72 + sub * 8]) = v;
    }
    __syncthreads();

    // S = Q K^T : 16 q rows x 64 keys
    f32x4 sv[4];
#pragma unroll
    for (int j = 0; j < 4; ++j) sv[j] = f32x4{0.f, 0.f, 0.f, 0.f};
#pragma unroll
    for (int kk = 0; kk < 4; ++kk) {
#pragma unroll
      for (int j = 0; j < 4; ++j) {
        bf16x8 kf = *reinterpret_cast<const bf16x8*>(&Klds[(j * 16 + l15) * 136 + kk * 32 + l4 * 8]);
        sv[j] = __builtin_amdgcn_mfma_f32_16x16x32_bf16(qf[kk], kf, sv[j], 0, 0, 0);
      }
    }

    // mask + scale + online softmax (per r: q row = q0 + wave*16 + l4*4 + r)
    const int qrow_base = q0 + wave * 16 + l4 * 4;
    float corr[4];
#pragma unroll
    for (int r = 0; r < 4; ++r) {
      int q = qrow_base + r;
      float tm = -1e30f;
#pragma unroll
      for (int j = 0; j < 4; ++j) {
        int key = kt * 64 + j * 16 + l15;
        float s = sv[j][r] * scale;
        s = (key <= q) ? s : -1e30f;
        sv[j][r] = s;
        tm = fmaxf(tm, s);
      }
#pragma unroll
      for (int off = 1; off < 16; off <<= 1) tm = fmaxf(tm, __shfl_xor(tm, off));
      float mnew = fmaxf(mrun[r], tm);
      corr[r] = __expf(mrun[r] - mnew);
      mrun[r] = mnew;
      float rs = 0.f;
#pragma unroll
      for (int j = 0; j < 4; ++j) {
        float p = __expf(sv[j][r] - mnew);
        sv[j][r] = p;
        rs += p;
      }
#pragma unroll
      for (int off = 1; off < 16; off <<= 1) rs += __shfl_xor(rs, off);
      lrun[r] = lrun[r] * corr[r] + rs;
    }
#pragma unroll
    for (int jd = 0; jd < 8; ++jd)
#pragma unroll
      for (int r = 0; r < 4; ++r) accO[jd][r] *= corr[r];

    // P -> LDS (C-layout scatter), then read back in A-operand layout
#pragma unroll
    for (int r = 0; r < 4; ++r)
#pragma unroll
      for (int j = 0; j < 4; ++j)
        Plds[wave][(l4 * 4 + r) * 72 + j * 16 + l15] = f2bf(sv[j][r]);

    // PV: O += P V
#pragma unroll
    for (int ks = 0; ks < 2; ++ks) {
      bf16x8 pf = *reinterpret_cast<const bf16x8*>(&Plds[wave][l15 * 72 + ks * 32 + l4 * 8]);
#pragma unroll
      for (int jd = 0; jd < 8; ++jd) {
        bf16x8 vf = *reinterpret_cast<const bf16x8*>(&Vt[(jd * 16 + l15) * 72 + ks * 32 + l4 * 8]);
        accO[jd] = __builtin_amdgcn_mfma_f32_16x16x32_bf16(pf, vf, accO[jd], 0, 0, 0);
      }
    }
    __syncthreads();
  }

  // epilogue: O / l
#pragma unroll
  for (int r = 0; r < 4; ++r) {
    float inv = 1.0f / lrun[r];
    int row = q0 + wave * 16 + l4 * 4 + r;
    size_t orow = ((size_t)b * SEQ_L + row) * (size_t)D_DIM + h * HEAD_DIM;
#pragma unroll
    for (int jd = 0; jd < 8; ++jd)
      obuf[orow + jd * 16 + l15] = f2bf(accO[jd][r] * inv);
  }
}

// ---------------- launcher ----------------
extern "C" void kernel_launch(void* const* d_in, const int* in_sizes, int n_in,
                              void* d_out, int out_size, void* d_ws, size_t ws_size,
                              hipStream_t stream) {
  const float* x   = (const float*)d_in[0];
  const float* wq  = (const float*)d_in[1];
  const float* wk  = (const float*)d_in[2];
  const float* wv  = (const float*)d_in[3];
  const float* wo  = (const float*)d_in[4];
  const float* qnw = (const float*)d_in[5];
  const float* knw = (const float*)d_in[6];
  float* out = (float*)d_out;

  char* ws = (char*)d_ws;
  unsigned short* Xb   = (unsigned short*)(ws);                 // [4096][2048]
  unsigned short* Wqkb = (unsigned short*)(ws + 16777216);      // [2560][2048]
  unsigned short* Wvb  = (unsigned short*)(ws + 27262976);      // [512][2048]
  unsigned short* Wob  = (unsigned short*)(ws + 29360128);      // [2048][2048]
  unsigned short* QKb  = (unsigned short*)(ws + 37748736);      // [4096][2560]
  unsigned short* VTb  = (unsigned short*)(ws + 58720256);      // [512][4096]
  unsigned short* Obuf = (unsigned short*)(ws + 62914560);      // [4096][2048]
  float* cosT = (float*)(ws + 79691776);                        // [2048][64]
  float* sinT = (float*)(ws + 80216064);

  cast_kernel<<<1024, 256, 0, stream>>>(x, Xb, NTOK * D_DIM);
  cast_kernel<<<1024, 256, 0, stream>>>(wq, Wqkb, D_DIM * D_DIM);
  cast_kernel<<<256, 256, 0, stream>>>(wk, Wqkb + (size_t)D_DIM * D_DIM, 512 * D_DIM);
  cast_kernel<<<256, 256, 0, stream>>>(wv, Wvb, 512 * D_DIM);
  cast_kernel<<<1024, 256, 0, stream>>>(wo, Wob, D_DIM * D_DIM);
  rope_table_kernel<<<512, 256, 0, stream>>>(cosT, sinT);

  // QK projection: [4096][2560]
  dim3 g1(NTOK / 128, NQK / 128);
  gemm_bt_kernel<unsigned short><<<g1, 256, 0, stream>>>(Xb, Wqkb, QKb, NTOK, NQK, D_DIM);

  // V^T directly: VT[dv][token] = sum_k Wv[dv][k] X[token][k]
  dim3 gv(512 / 128, NTOK / 128);
  gemm_bt_kernel<unsigned short><<<gv, 256, 0, stream>>>(Wvb, Xb, VTb, 512, NTOK, D_DIM);

  norm_rope_kernel<<<(NTOK * (H_HEADS + KV_HEADS)) / 4, 256, 0, stream>>>(QKb, qnw, knw, cosT, sinT);

  attn_kernel<<<dim3(SEQ_L / 64, BATCH * H_HEADS), 256, 0, stream>>>(QKb, VTb, Obuf);

  dim3 g2(NTOK / 128, D_DIM / 128);
  gemm_bt_kernel<float><<<g2, 256, 0, stream>>>(Obuf, Wob, out, NTOK, D_DIM, D_DIM);
}

// Round 5
// 313.301 us; speedup vs baseline: 1.5735x; 1.5735x over previous
//
#include <hip/hip_runtime.h>
#include <hip/hip_bf16.h>
#include <stdint.h>
#include <stddef.h>

// Problem constants
#define D_DIM 2048
#define H_HEADS 16
#define KV_HEADS 4
#define HEAD_DIM 128
#define SEQ_L 2048
#define BATCH 2
#define NTOK 4096      // BATCH*SEQ_L
#define NQK 2560       // D + KV_HEADS*HEAD_DIM   (Q + K only; V handled separately)

typedef __attribute__((ext_vector_type(4))) float f32x4;
typedef __attribute__((ext_vector_type(16))) float f32x16;
typedef __attribute__((ext_vector_type(8))) short bf16x8;

__device__ __forceinline__ unsigned short f2bf(float f) {
  unsigned int u = __float_as_uint(f);
  unsigned int r = u + 0x7fffu + ((u >> 16) & 1u);   // RTNE
  return (unsigned short)(r >> 16);
}
__device__ __forceinline__ float bf2f(unsigned short s) {
  return __uint_as_float(((unsigned int)s) << 16);
}

__device__ __forceinline__ void async_copy16(const void* g, void* l) {
  __builtin_amdgcn_global_load_lds(
      (__attribute__((address_space(1))) void*)(g),
      (__attribute__((address_space(3))) void*)(l),
      16, 0, 0);
}

// ---------------- fp32 -> bf16 cast ----------------
__global__ __launch_bounds__(256) void cast_kernel(const float* __restrict__ src,
                                                   unsigned short* __restrict__ dst, int n) {
  int idx = blockIdx.x * blockDim.x + threadIdx.x;
  int stride = gridDim.x * blockDim.x;
  for (int i = idx * 4; i < n; i += stride * 4) {
    float4 v = *reinterpret_cast<const float4*>(src + i);
    ushort4 o;
    o.x = f2bf(v.x); o.y = f2bf(v.y); o.z = f2bf(v.z); o.w = f2bf(v.w);
    *reinterpret_cast<ushort4*>(dst + i) = o;
  }
}

// ---------------- RoPE table ----------------
__global__ __launch_bounds__(256) void rope_table_kernel(float* __restrict__ cosT,
                                                         float* __restrict__ sinT) {
  int i = blockIdx.x * blockDim.x + threadIdx.x;  // l*64 + p
  if (i >= SEQ_L * 64) return;
  int p = i & 63;
  float l = (float)(i >> 6);
  float inv = powf(10000.0f, -(float)p / 64.0f);
  float ang = l * inv;
  cosT[i] = cosf(ang);
  sinT[i] = sinf(ang);
}

// ---------------- GEMM: C[M,N] = A[M,K] * B[N,K]^T  (bf16 in, OutT out) ----------------
__device__ __forceinline__ void store_out(unsigned short* p, float v) { *p = f2bf(v); }
__device__ __forceinline__ void store_out(float* p, float v) { *p = v; }

template <typename OutT>
__global__ __launch_bounds__(256) void gemm_bt_kernel(const unsigned short* __restrict__ A,
                                                      const unsigned short* __restrict__ B,
                                                      OutT* __restrict__ C,
                                                      int M, int N, int K) {
  __shared__ unsigned short Alds[128 * 32];
  __shared__ unsigned short Blds[128 * 32];
  const int tid = threadIdx.x;
  const int wave = tid >> 6;
  const int lane = tid & 63;
  const int l15 = lane & 15;
  const int l4 = lane >> 4;
  const int m0 = blockIdx.x * 128;
  const int n0 = blockIdx.y * 128;
  const int wm = (wave >> 1) * 64;
  const int wn = (wave & 1) * 64;

  f32x4 acc[4][4] = {};

  const int soff0 = wave * 1024 + lane * 16;  // bytes within 8KB tile

  for (int kt = 0; kt < K; kt += 32) {
#pragma unroll
    for (int inst = 0; inst < 2; ++inst) {
      int off = soff0 + inst * 4096;
      int row = off >> 6;    // 64 bytes (32 bf16) per LDS row
      int colb = off & 63;
      const char* ga = (const char*)(A + (size_t)(m0 + row) * K + kt) + colb;
      async_copy16(ga, (char*)Alds + off);
      const char* gb = (const char*)(B + (size_t)(n0 + row) * K + kt) + colb;
      async_copy16(gb, (char*)Blds + off);
    }
    __syncthreads();
    bf16x8 af[4], bfr[4];
#pragma unroll
    for (int i = 0; i < 4; ++i)
      af[i] = *reinterpret_cast<const bf16x8*>(Alds + (wm + i * 16 + l15) * 32 + l4 * 8);
#pragma unroll
    for (int j = 0; j < 4; ++j)
      bfr[j] = *reinterpret_cast<const bf16x8*>(Blds + (wn + j * 16 + l15) * 32 + l4 * 8);
#pragma unroll
    for (int i = 0; i < 4; ++i)
#pragma unroll
      for (int j = 0; j < 4; ++j)
        acc[i][j] = __builtin_amdgcn_mfma_f32_16x16x32_bf16(af[i], bfr[j], acc[i][j], 0, 0, 0);
    __syncthreads();
  }

#pragma unroll
  for (int i = 0; i < 4; ++i)
#pragma unroll
    for (int j = 0; j < 4; ++j) {
      int col = n0 + wn + j * 16 + l15;
#pragma unroll
      for (int r = 0; r < 4; ++r) {
        int row = m0 + wm + i * 16 + l4 * 4 + r;
        store_out(C + (size_t)row * N + col, acc[i][j][r]);
      }
    }
}

// ---------------- RMSNorm + RoPE (in-place on QK buffer, stride NQK) ----------------
__global__ __launch_bounds__(256) void norm_rope_kernel(unsigned short* __restrict__ qk,
                                                        const float* __restrict__ qw,
                                                        const float* __restrict__ kw,
                                                        const float* __restrict__ cosT,
                                                        const float* __restrict__ sinT) {
  int wid = (blockIdx.x * blockDim.x + threadIdx.x) >> 6;  // global wave id
  int lane = threadIdx.x & 63;
  unsigned short* rowp;
  const float* w;
  int m;
  if (wid < NTOK * H_HEADS) {
    m = wid >> 4;
    int hh = wid & 15;
    rowp = qk + (size_t)m * NQK + hh * HEAD_DIM;
    w = qw;
  } else {
    int r2 = wid - NTOK * H_HEADS;
    m = r2 >> 2;
    int kvh = r2 & 3;
    rowp = qk + (size_t)m * NQK + D_DIM + kvh * HEAD_DIM;
    w = kw;
  }
  int l = m & (SEQ_L - 1);
  unsigned int pair = *reinterpret_cast<const unsigned int*>(rowp + lane * 2);
  float e = bf2f((unsigned short)(pair & 0xffffu));
  float o = bf2f((unsigned short)(pair >> 16));
  float ss = e * e + o * o;
#pragma unroll
  for (int off = 1; off < 64; off <<= 1) ss += __shfl_xor(ss, off);
  float rsn = rsqrtf(ss * (1.0f / 128.0f) + 1e-6f);
  float we = w[lane * 2], wo_ = w[lane * 2 + 1];
  float c = cosT[l * 64 + lane], s = sinT[l * 64 + lane];
  float xe = e * rsn * we, xo = o * rsn * wo_;
  float re = xe * c - xo * s;
  float ro = xe * s + xo * c;
  unsigned int opack = (unsigned int)f2bf(re) | ((unsigned int)f2bf(ro) << 16);
  *reinterpret_cast<unsigned int*>(rowp + lane * 2) = opack;
}

// ---------------- Flash attention v4: swapped-QK 32x32, KVBLK=64, dbuf ----------------
// Block: 256 threads = 4 waves; each wave owns 32 q rows; block = 128 q rows.
// qk: [NTOK][NQK] bf16 (post norm+rope).  vt: [512][NTOK] bf16 = V^T per (kvh,d).
// FIX vs v2/v3: the per-tile O-rescale now uses reg-row-attributed corr
// (accO rows are q=(r&3)+8*(r>>2)+4*hi, NOT the lane-owned q=l31).
__global__ __launch_bounds__(256, 2) void attn_kernel(const unsigned short* __restrict__ qk,
                                                      const unsigned short* __restrict__ vt,
                                                      unsigned short* __restrict__ obuf) {
  __shared__ unsigned short Kl[2][64 * 128];   // [key][d], XOR-swizzled rows (256B)
  __shared__ unsigned short Vl[2][128 * 64];   // [d][key], XOR-swizzled rows (128B)
  __shared__ float invl[128];

  const int tid = threadIdx.x;
  const int w = tid >> 6, lane = tid & 63;
  const int l31 = lane & 31, hi = lane >> 5;
  const int qt = gridDim.x - 1 - blockIdx.x;   // longest-first (LPT)
  const int q0 = qt * 128;
  const int bh = blockIdx.y;
  const int b = bh >> 4, h = bh & 15, kvh = h >> 2;

  const unsigned short* Qg = qk + (size_t)(b * SEQ_L + q0 + w * 32 + l31) * NQK + h * HEAD_DIM;
  const unsigned short* Kg = qk + (size_t)(b * SEQ_L) * NQK + D_DIM + kvh * HEAD_DIM;
  const unsigned short* Vg = vt + (size_t)(kvh * HEAD_DIM) * NTOK + b * SEQ_L;

  // Q fragments in registers: qf[kk] = Q[q=l31][kk*16 + hi*8 .. +7]
  bf16x8 qf[8];
#pragma unroll
  for (int kk = 0; kk < 8; ++kk)
    qf[kk] = *reinterpret_cast<const bf16x8*>(Qg + kk * 16 + hi * 8);

  f32x16 accO[4] = {};
  float m_run = -1e30f, l_run = 0.0f;

  const int qmin_w = q0 + w * 32;
  const int qmax_w = qmin_w + 31;
  const int qg = qmin_w + l31;
  const int ntiles = (q0 + 128) >> 6;
  const float scale = 0.08838834764831845f;  // 1/sqrt(128)

  auto stage = [&](int bb, int kt) {
#pragma unroll
    for (int i = 0; i < 4; ++i) {
      int o = (i * 256 + tid) * 16;   // byte offset of this thread's 16B slot
      {  // K tile: [64 rows][256B], swz: byte ^= ((row&7)<<4)
        int row = o >> 8;
        int scb = (o & 255) ^ ((row & 7) << 4);
        const char* src = (const char*)(Kg + (size_t)(kt * 64 + row) * NQK) + scb;
        async_copy16(src, (char*)(&Kl[bb][0]) + o);
      }
      {  // V^T tile: [128 rows][128B], swz: byte ^= ((d&7)<<4)
        int d = o >> 7;
        int skb = (o & 127) ^ ((d & 7) << 4);
        const char* src = (const char*)(Vg + (size_t)d * NTOK + kt * 64) + skb;
        async_copy16(src, (char*)(&Vl[bb][0]) + o);
      }
    }
  };

  stage(0, 0);
  asm volatile("s_waitcnt vmcnt(0)" ::: "memory");
  __syncthreads();

  int buf = 0;
  for (int kt = 0; kt < ntiles; ++kt) {
    if (kt + 1 < ntiles) stage(buf ^ 1, kt + 1);

    if (kt * 64 <= qmax_w) {   // wave-uniform: skip fully-masked tiles
      // ---- QK^T: S^T[key][q], two 32-key sub-tiles ----
      f32x16 st[2] = {};
#pragma unroll
      for (int stile = 0; stile < 2; ++stile) {
#pragma unroll
        for (int kk = 0; kk < 8; ++kk) {
          int row = stile * 32 + l31;
          int off = (row << 8) + (((kk << 5) + (hi << 4)) ^ ((l31 & 7) << 4));
          bf16x8 kf = *reinterpret_cast<const bf16x8*>((const char*)(&Kl[buf][0]) + off);
          st[stile] = __builtin_amdgcn_mfma_f32_32x32x16_bf16(kf, qf[kk], st[stile], 0, 0, 0);
        }
      }

      // ---- mask + scale + per-lane online softmax (lane owns q-row = l31) ----
      const bool need_mask = (kt * 64 + 63 > qmin_w);
      float tmax = -1e30f;
#pragma unroll
      for (int stile = 0; stile < 2; ++stile)
#pragma unroll
        for (int r = 0; r < 16; ++r) {
          float s = st[stile][r] * scale;
          if (need_mask) {
            int key = kt * 64 + stile * 32 + (r & 3) + ((r >> 2) << 3) + (hi << 2);
            if (key > qg) s = -1e30f;
          }
          st[stile][r] = s;
          tmax = fmaxf(tmax, s);
        }
      tmax = fmaxf(tmax, __shfl_xor(tmax, 32));
      float mnew = fmaxf(m_run, tmax);
      float corr = __expf(m_run - mnew);
      m_run = mnew;
      float rsum = 0.0f;
#pragma unroll
      for (int stile = 0; stile < 2; ++stile)
#pragma unroll
        for (int r = 0; r < 16; ++r) {
          float pe = __expf(st[stile][r] - mnew);
          st[stile][r] = pe;
          rsum += pe;
        }
      rsum += __shfl_xor(rsum, 32);
      l_run = l_run * corr + rsum;

      // ---- rescale O with REG-ROW-attributed corr (THE FIX) ----
      // accO[dt][r] belongs to q-row (r&3)+8*(r>>2)+4*hi; lane qi holds corr
      // for q-row qi (identical on both hi-halves after the shfl_xor(32) max).
      float corrq[16];
#pragma unroll
      for (int r = 0; r < 16; ++r) {
        int qi = (r & 3) + ((r >> 2) << 3) + (hi << 2);
        corrq[r] = __shfl(corr, qi);
      }
#pragma unroll
      for (int dt = 0; dt < 4; ++dt)
#pragma unroll
        for (int r = 0; r < 16; ++r) accO[dt][r] *= corrq[r];

      // ---- P -> bf16 A-fragments: pack + half-exchange (shfl_xor + select) ----
      bf16x8 pa[2][2];
#pragma unroll
      for (int stile = 0; stile < 2; ++stile)
#pragma unroll
        for (int kc = 0; kc < 2; ++kc) {
          int rb = kc * 8;
          unsigned x0 = (unsigned)f2bf(st[stile][rb + 0]) | ((unsigned)f2bf(st[stile][rb + 1]) << 16);
          unsigned y0 = (unsigned)f2bf(st[stile][rb + 4]) | ((unsigned)f2bf(st[stile][rb + 5]) << 16);
          unsigned x1 = (unsigned)f2bf(st[stile][rb + 2]) | ((unsigned)f2bf(st[stile][rb + 3]) << 16);
          unsigned y1 = (unsigned)f2bf(st[stile][rb + 6]) | ((unsigned)f2bf(st[stile][rb + 7]) << 16);
          unsigned x0s = (unsigned)__shfl_xor((int)x0, 32);
          unsigned y0s = (unsigned)__shfl_xor((int)y0, 32);
          unsigned x1s = (unsigned)__shfl_xor((int)x1, 32);
          unsigned y1s = (unsigned)__shfl_xor((int)y1, 32);
          unsigned w0 = hi ? y0s : x0;   // keys hi*8 + {0,1}
          unsigned w2 = hi ? y0 : x0s;   // keys hi*8 + {4,5}
          unsigned w1 = hi ? y1s : x1;   // keys hi*8 + {2,3}
          unsigned w3 = hi ? y1 : x1s;   // keys hi*8 + {6,7}
          union { bf16x8 v; unsigned u[4]; } uu;
          uu.u[0] = w0; uu.u[1] = w1; uu.u[2] = w2; uu.u[3] = w3;
          pa[stile][kc] = uu.v;
        }

      // ---- PV: O[q][d] += P * V ----
#pragma unroll
      for (int dt = 0; dt < 4; ++dt) {
        int drow = dt * 32 + l31;
#pragma unroll
        for (int stile = 0; stile < 2; ++stile)
#pragma unroll
          for (int kc = 0; kc < 2; ++kc) {
            int off = (drow << 7) + (((stile << 6) + (kc << 5) + (hi << 4)) ^ ((l31 & 7) << 4));
            bf16x8 vf = *reinterpret_cast<const bf16x8*>((const char*)(&Vl[buf][0]) + off);
            accO[dt] = __builtin_amdgcn_mfma_f32_32x32x16_bf16(pa[stile][kc], vf, accO[dt], 0, 0, 0);
          }
      }
    }

    asm volatile("s_waitcnt vmcnt(0)" ::: "memory");
    __syncthreads();
    buf ^= 1;
  }

  // ---- epilogue: O /= l (1/l redistributed via tiny LDS table) ----
  if (hi == 0) invl[w * 32 + l31] = 1.0f / l_run;
  __syncthreads();
#pragma unroll
  for (int dt = 0; dt < 4; ++dt)
#pragma unroll
    for (int r = 0; r < 16; ++r) {
      int qrow = (r & 3) + ((r >> 2) << 3) + (hi << 2);
      float val = accO[dt][r] * invl[w * 32 + qrow];
      int tok = b * SEQ_L + q0 + w * 32 + qrow;
      obuf[(size_t)tok * D_DIM + h * HEAD_DIM + dt * 32 + l31] = f2bf(val);
    }
}

// ---------------- launcher ----------------
extern "C" void kernel_launch(void* const* d_in, const int* in_sizes, int n_in,
                              void* d_out, int out_size, void* d_ws, size_t ws_size,
                              hipStream_t stream) {
  const float* x   = (const float*)d_in[0];
  const float* wq  = (const float*)d_in[1];
  const float* wk  = (const float*)d_in[2];
  const float* wv  = (const float*)d_in[3];
  const float* wo  = (const float*)d_in[4];
  const float* qnw = (const float*)d_in[5];
  const float* knw = (const float*)d_in[6];
  float* out = (float*)d_out;

  char* ws = (char*)d_ws;
  unsigned short* Xb   = (unsigned short*)(ws);                 // [4096][2048]
  unsigned short* Wqkb = (unsigned short*)(ws + 16777216);      // [2560][2048]
  unsigned short* Wvb  = (unsigned short*)(ws + 27262976);      // [512][2048]
  unsigned short* Wob  = (unsigned short*)(ws + 29360128);      // [2048][2048]
  unsigned short* QKb  = (unsigned short*)(ws + 37748736);      // [4096][2560]
  unsigned short* VTb  = (unsigned short*)(ws + 58720256);      // [512][4096]
  unsigned short* Obuf = (unsigned short*)(ws + 62914560);      // [4096][2048]
  float* cosT = (float*)(ws + 79691776);                        // [2048][64]
  float* sinT = (float*)(ws + 80216064);

  cast_kernel<<<1024, 256, 0, stream>>>(x, Xb, NTOK * D_DIM);
  cast_kernel<<<1024, 256, 0, stream>>>(wq, Wqkb, D_DIM * D_DIM);
  cast_kernel<<<256, 256, 0, stream>>>(wk, Wqkb + (size_t)D_DIM * D_DIM, 512 * D_DIM);
  cast_kernel<<<256, 256, 0, stream>>>(wv, Wvb, 512 * D_DIM);
  cast_kernel<<<1024, 256, 0, stream>>>(wo, Wob, D_DIM * D_DIM);
  rope_table_kernel<<<512, 256, 0, stream>>>(cosT, sinT);

  // QK projection: [4096][2560]
  dim3 g1(NTOK / 128, NQK / 128);
  gemm_bt_kernel<unsigned short><<<g1, 256, 0, stream>>>(Xb, Wqkb, QKb, NTOK, NQK, D_DIM);

  // V^T directly: VT[dv][token] = sum_k Wv[dv][k] X[token][k]
  dim3 gv(512 / 128, NTOK / 128);
  gemm_bt_kernel<unsigned short><<<gv, 256, 0, stream>>>(Wvb, Xb, VTb, 512, NTOK, D_DIM);

  norm_rope_kernel<<<(NTOK * (H_HEADS + KV_HEADS)) / 4, 256, 0, stream>>>(QKb, qnw, knw, cosT, sinT);

  attn_kernel<<<dim3(SEQ_L / 128, BATCH * H_HEADS), 256, 0, stream>>>(QKb, VTb, Obuf);

  dim3 g2(NTOK / 128, D_DIM / 128);
  gemm_bt_kernel<float><<<g2, 256, 0, stream>>>(Obuf, Wob, out, NTOK, D_DIM, D_DIM);
}

// Round 7
// 305.188 us; speedup vs baseline: 1.6154x; 1.0266x over previous
//
#include <hip/hip_runtime.h>
#include <hip/hip_bf16.h>
#include <stdint.h>
#include <stddef.h>

// Problem constants
#define D_DIM 2048
#define H_HEADS 16
#define KV_HEADS 4
#define HEAD_DIM 128
#define SEQ_L 2048
#define BATCH 2
#define NTOK 4096      // BATCH*SEQ_L
#define NQK 2560       // D + KV_HEADS*HEAD_DIM   (Q + K only; V handled separately)

typedef __attribute__((ext_vector_type(4))) float f32x4;
typedef __attribute__((ext_vector_type(16))) float f32x16;
typedef __attribute__((ext_vector_type(8))) short bf16x8;

__device__ __forceinline__ unsigned short f2bf(float f) {
  __hip_bfloat16 h = __float2bfloat16(f);            // RTNE
  return *reinterpret_cast<unsigned short*>(&h);
}
__device__ __forceinline__ unsigned pack2(float lo, float hi) {
  return (unsigned)f2bf(lo) | ((unsigned)f2bf(hi) << 16);
}
__device__ __forceinline__ float bf2f(unsigned short s) {
  return __uint_as_float(((unsigned int)s) << 16);
}

__device__ __forceinline__ void async_copy16(const void* g, void* l) {
  __builtin_amdgcn_global_load_lds(
      (__attribute__((address_space(1))) void*)(g),
      (__attribute__((address_space(3))) void*)(l),
      16, 0, 0);
}

// ---------------- fp32 -> bf16 cast ----------------
__global__ __launch_bounds__(256) void cast_kernel(const float* __restrict__ src,
                                                   unsigned short* __restrict__ dst, int n) {
  int idx = blockIdx.x * blockDim.x + threadIdx.x;
  int stride = gridDim.x * blockDim.x;
  for (int i = idx * 4; i < n; i += stride * 4) {
    float4 v = *reinterpret_cast<const float4*>(src + i);
    uint2 o;
    o.x = pack2(v.x, v.y);
    o.y = pack2(v.z, v.w);
    *reinterpret_cast<uint2*>(dst + i) = o;
  }
}

// ---------------- RoPE table ----------------
__global__ __launch_bounds__(256) void rope_table_kernel(float* __restrict__ cosT,
                                                         float* __restrict__ sinT) {
  int i = blockIdx.x * blockDim.x + threadIdx.x;  // l*64 + p
  if (i >= SEQ_L * 64) return;
  int p = i & 63;
  float l = (float)(i >> 6);
  float inv = powf(10000.0f, -(float)p / 64.0f);
  float ang = l * inv;
  cosT[i] = cosf(ang);
  sinT[i] = sinf(ang);
}

// ---------------- GEMM: C[M,N] = A[M,K] * B[N,K]^T  (bf16 in, OutT out) ----------------
__device__ __forceinline__ void store_out(unsigned short* p, float v) { *p = f2bf(v); }
__device__ __forceinline__ void store_out(float* p, float v) { *p = v; }

template <typename OutT>
__global__ __launch_bounds__(256) void gemm_bt_kernel(const unsigned short* __restrict__ A,
                                                      const unsigned short* __restrict__ B,
                                                      OutT* __restrict__ C,
                                                      int M, int N, int K) {
  __shared__ unsigned short Alds[128 * 32];
  __shared__ unsigned short Blds[128 * 32];
  const int tid = threadIdx.x;
  const int wave = tid >> 6;
  const int lane = tid & 63;
  const int l15 = lane & 15;
  const int l4 = lane >> 4;
  const int m0 = blockIdx.x * 128;
  const int n0 = blockIdx.y * 128;
  const int wm = (wave >> 1) * 64;
  const int wn = (wave & 1) * 64;

  f32x4 acc[4][4] = {};

  const int soff0 = wave * 1024 + lane * 16;  // bytes within 8KB tile

  for (int kt = 0; kt < K; kt += 32) {
#pragma unroll
    for (int inst = 0; inst < 2; ++inst) {
      int off = soff0 + inst * 4096;
      int row = off >> 6;    // 64 bytes (32 bf16) per LDS row
      int colb = off & 63;
      const char* ga = (const char*)(A + (size_t)(m0 + row) * K + kt) + colb;
      async_copy16(ga, (char*)Alds + off);
      const char* gb = (const char*)(B + (size_t)(n0 + row) * K + kt) + colb;
      async_copy16(gb, (char*)Blds + off);
    }
    __syncthreads();
    bf16x8 af[4], bfr[4];
#pragma unroll
    for (int i = 0; i < 4; ++i)
      af[i] = *reinterpret_cast<const bf16x8*>(Alds + (wm + i * 16 + l15) * 32 + l4 * 8);
#pragma unroll
    for (int j = 0; j < 4; ++j)
      bfr[j] = *reinterpret_cast<const bf16x8*>(Blds + (wn + j * 16 + l15) * 32 + l4 * 8);
#pragma unroll
    for (int i = 0; i < 4; ++i)
#pragma unroll
      for (int j = 0; j < 4; ++j)
        acc[i][j] = __builtin_amdgcn_mfma_f32_16x16x32_bf16(af[i], bfr[j], acc[i][j], 0, 0, 0);
    __syncthreads();
  }

#pragma unroll
  for (int i = 0; i < 4; ++i)
#pragma unroll
    for (int j = 0; j < 4; ++j) {
      int col = n0 + wn + j * 16 + l15;
#pragma unroll
      for (int r = 0; r < 4; ++r) {
        int row = m0 + wm + i * 16 + l4 * 4 + r;
        store_out(C + (size_t)row * N + col, acc[i][j][r]);
      }
    }
}

// ---------------- RMSNorm + RoPE (in-place on QK buffer, stride NQK) ----------------
// Also folds the attention scale 1/sqrt(HD) into Q rows.
__global__ __launch_bounds__(256) void norm_rope_kernel(unsigned short* __restrict__ qk,
                                                        const float* __restrict__ qw,
                                                        const float* __restrict__ kw,
                                                        const float* __restrict__ cosT,
                                                        const float* __restrict__ sinT) {
  int wid = (blockIdx.x * blockDim.x + threadIdx.x) >> 6;  // global wave id
  int lane = threadIdx.x & 63;
  unsigned short* rowp;
  const float* w;
  int m;
  float sc;
  if (wid < NTOK * H_HEADS) {
    m = wid >> 4;
    int hh = wid & 15;
    rowp = qk + (size_t)m * NQK + hh * HEAD_DIM;
    w = qw;
    sc = 0.08838834764831845f;   // fold 1/sqrt(128) into Q
  } else {
    int r2 = wid - NTOK * H_HEADS;
    m = r2 >> 2;
    int kvh = r2 & 3;
    rowp = qk + (size_t)m * NQK + D_DIM + kvh * HEAD_DIM;
    w = kw;
    sc = 1.0f;
  }
  int l = m & (SEQ_L - 1);
  unsigned int pair = *reinterpret_cast<const unsigned int*>(rowp + lane * 2);
  float e = bf2f((unsigned short)(pair & 0xffffu));
  float o = bf2f((unsigned short)(pair >> 16));
  float ss = e * e + o * o;
#pragma unroll
  for (int off = 1; off < 64; off <<= 1) ss += __shfl_xor(ss, off);
  float rsn = rsqrtf(ss * (1.0f / 128.0f) + 1e-6f) * sc;
  float we = w[lane * 2], wo_ = w[lane * 2 + 1];
  float c = cosT[l * 64 + lane], s = sinT[l * 64 + lane];
  float xe = e * rsn * we, xo = o * rsn * wo_;
  float re = xe * c - xo * s;
  float ro = xe * s + xo * c;
  *reinterpret_cast<unsigned int*>(rowp + lane * 2) = pack2(re, ro);
}

// ---------------- Flash attention v5: swapped-QK 32x32, KVBLK=64, dbuf ----------------
// v5 = v4 + {scale folded into Q, defer-max (THR=8), setprio}.
__global__ __launch_bounds__(256, 2) void attn_kernel(const unsigned short* __restrict__ qk,
                                                      const unsigned short* __restrict__ vt,
                                                      unsigned short* __restrict__ obuf) {
  __shared__ unsigned short Kl[2][64 * 128];   // [key][d], XOR-swizzled rows (256B)
  __shared__ unsigned short Vl[2][128 * 64];   // [d][key], XOR-swizzled rows (128B)
  __shared__ float invl[128];

  const int tid = threadIdx.x;
  const int w = tid >> 6, lane = tid & 63;
  const int l31 = lane & 31, hi = lane >> 5;
  const int qt = gridDim.x - 1 - blockIdx.x;   // longest-first (LPT)
  const int q0 = qt * 128;
  const int bh = blockIdx.y;
  const int b = bh >> 4, h = bh & 15, kvh = h >> 2;

  const unsigned short* Qg = qk + (size_t)(b * SEQ_L + q0 + w * 32 + l31) * NQK + h * HEAD_DIM;
  const unsigned short* Kg = qk + (size_t)(b * SEQ_L) * NQK + D_DIM + kvh * HEAD_DIM;
  const unsigned short* Vg = vt + (size_t)(kvh * HEAD_DIM) * NTOK + b * SEQ_L;

  // Q fragments in registers: qf[kk] = Q[q=l31][kk*16 + hi*8 .. +7]
  bf16x8 qf[8];
#pragma unroll
  for (int kk = 0; kk < 8; ++kk)
    qf[kk] = *reinterpret_cast<const bf16x8*>(Qg + kk * 16 + hi * 8);

  f32x16 accO[4] = {};
  float m_run = -1e30f, l_run = 0.0f;

  const int qmin_w = q0 + w * 32;
  const int qmax_w = qmin_w + 31;
  const int qg = qmin_w + l31;
  const int ntiles = (q0 + 128) >> 6;

  auto stage = [&](int bb, int kt) {
#pragma unroll
    for (int i = 0; i < 4; ++i) {
      int o = (i * 256 + tid) * 16;   // byte offset of this thread's 16B slot
      {  // K tile: [64 rows][256B], swz: byte ^= ((row&7)<<4)
        int row = o >> 8;
        int scb = (o & 255) ^ ((row & 7) << 4);
        const char* src = (const char*)(Kg + (size_t)(kt * 64 + row) * NQK) + scb;
        async_copy16(src, (char*)(&Kl[bb][0]) + o);
      }
      {  // V^T tile: [128 rows][128B], swz: byte ^= ((d&7)<<4)
        int d = o >> 7;
        int skb = (o & 127) ^ ((d & 7) << 4);
        const char* src = (const char*)(Vg + (size_t)d * NTOK + kt * 64) + skb;
        async_copy16(src, (char*)(&Vl[bb][0]) + o);
      }
    }
  };

  stage(0, 0);
  asm volatile("s_waitcnt vmcnt(0)" ::: "memory");
  __syncthreads();

  int buf = 0;
  for (int kt = 0; kt < ntiles; ++kt) {
    if (kt + 1 < ntiles) stage(buf ^ 1, kt + 1);

    if (kt * 64 <= qmax_w) {   // wave-uniform: skip fully-masked tiles
      // ---- QK^T: S^T[key][q], two 32-key sub-tiles ----
      f32x16 st[2] = {};
      __builtin_amdgcn_s_setprio(1);
#pragma unroll
      for (int stile = 0; stile < 2; ++stile) {
#pragma unroll
        for (int kk = 0; kk < 8; ++kk) {
          int row = stile * 32 + l31;
          int off = (row << 8) + (((kk << 5) + (hi << 4)) ^ ((l31 & 7) << 4));
          bf16x8 kf = *reinterpret_cast<const bf16x8*>((const char*)(&Kl[buf][0]) + off);
          st[stile] = __builtin_amdgcn_mfma_f32_32x32x16_bf16(kf, qf[kk], st[stile], 0, 0, 0);
        }
      }
      __builtin_amdgcn_s_setprio(0);

      // ---- mask + per-lane online softmax (scale pre-folded into Q) ----
      const bool need_mask = (kt * 64 + 63 > qmin_w);
      float tmax = -1e30f;
#pragma unroll
      for (int stile = 0; stile < 2; ++stile)
#pragma unroll
        for (int r = 0; r < 16; ++r) {
          float s = st[stile][r];
          if (need_mask) {
            int key = kt * 64 + stile * 32 + (r & 3) + ((r >> 2) << 3) + (hi << 2);
            if (key > qg) s = -1e30f;
          }
          st[stile][r] = s;
          tmax = fmaxf(tmax, s);
        }
      tmax = fmaxf(tmax, __shfl_xor(tmax, 32));

      // ---- defer-max (T13): only rescale when the running max grew > THR ----
      if (!__all(tmax - m_run <= 8.0f)) {
        float mnew = fmaxf(m_run, tmax);
        float corr = __expf(m_run - mnew);
        m_run = mnew;
        l_run *= corr;
        // redistribute corr to reg-row attribution, rescale O
        float corrq[16];
#pragma unroll
        for (int r = 0; r < 16; ++r) {
          int qi = (r & 3) + ((r >> 2) << 3) + (hi << 2);
          corrq[r] = __shfl(corr, qi);
        }
#pragma unroll
        for (int dt = 0; dt < 4; ++dt)
#pragma unroll
          for (int r = 0; r < 16; ++r) accO[dt][r] *= corrq[r];
      }

      float rsum = 0.0f;
#pragma unroll
      for (int stile = 0; stile < 2; ++stile)
#pragma unroll
        for (int r = 0; r < 16; ++r) {
          float pe = __expf(st[stile][r] - m_run);
          st[stile][r] = pe;
          rsum += pe;
        }
      rsum += __shfl_xor(rsum, 32);
      l_run += rsum;

      // ---- P -> bf16 A-fragments: pack + half-exchange (shfl_xor + select) ----
      bf16x8 pa[2][2];
#pragma unroll
      for (int stile = 0; stile < 2; ++stile)
#pragma unroll
        for (int kc = 0; kc < 2; ++kc) {
          int rb = kc * 8;
          unsigned x0 = pack2(st[stile][rb + 0], st[stile][rb + 1]);
          unsigned y0 = pack2(st[stile][rb + 4], st[stile][rb + 5]);
          unsigned x1 = pack2(st[stile][rb + 2], st[stile][rb + 3]);
          unsigned y1 = pack2(st[stile][rb + 6], st[stile][rb + 7]);
          unsigned x0s = (unsigned)__shfl_xor((int)x0, 32);
          unsigned y0s = (unsigned)__shfl_xor((int)y0, 32);
          unsigned x1s = (unsigned)__shfl_xor((int)x1, 32);
          unsigned y1s = (unsigned)__shfl_xor((int)y1, 32);
          unsigned w0 = hi ? y0s : x0;   // keys hi*8 + {0,1}
          unsigned w2 = hi ? y0 : x0s;   // keys hi*8 + {4,5}
          unsigned w1 = hi ? y1s : x1;   // keys hi*8 + {2,3}
          unsigned w3 = hi ? y1 : x1s;   // keys hi*8 + {6,7}
          union { bf16x8 v; unsigned u[4]; } uu;
          uu.u[0] = w0; uu.u[1] = w1; uu.u[2] = w2; uu.u[3] = w3;
          pa[stile][kc] = uu.v;
        }

      // ---- PV: O[q][d] += P * V ----
      __builtin_amdgcn_s_setprio(1);
#pragma unroll
      for (int dt = 0; dt < 4; ++dt) {
        int drow = dt * 32 + l31;
#pragma unroll
        for (int stile = 0; stile < 2; ++stile)
#pragma unroll
          for (int kc = 0; kc < 2; ++kc) {
            int off = (drow << 7) + (((stile << 6) + (kc << 5) + (hi << 4)) ^ ((l31 & 7) << 4));
            bf16x8 vf = *reinterpret_cast<const bf16x8*>((const char*)(&Vl[buf][0]) + off);
            accO[dt] = __builtin_amdgcn_mfma_f32_32x32x16_bf16(pa[stile][kc], vf, accO[dt], 0, 0, 0);
          }
      }
      __builtin_amdgcn_s_setprio(0);
    }

    asm volatile("s_waitcnt vmcnt(0)" ::: "memory");
    __syncthreads();
    buf ^= 1;
  }

  // ---- epilogue: O /= l (1/l redistributed via tiny LDS table) ----
  if (hi == 0) invl[w * 32 + l31] = 1.0f / l_run;
  __syncthreads();
#pragma unroll
  for (int dt = 0; dt < 4; ++dt)
#pragma unroll
    for (int r = 0; r < 16; ++r) {
      int qrow = (r & 3) + ((r >> 2) << 3) + (hi << 2);
      float val = accO[dt][r] * invl[w * 32 + qrow];
      int tok = b * SEQ_L + q0 + w * 32 + qrow;
      obuf[(size_t)tok * D_DIM + h * HEAD_DIM + dt * 32 + l31] = f2bf(val);
    }
}

// ---------------- launcher ----------------
extern "C" void kernel_launch(void* const* d_in, const int* in_sizes, int n_in,
                              void* d_out, int out_size, void* d_ws, size_t ws_size,
                              hipStream_t stream) {
  const float* x   = (const float*)d_in[0];
  const float* wq  = (const float*)d_in[1];
  const float* wk  = (const float*)d_in[2];
  const float* wv  = (const float*)d_in[3];
  const float* wo  = (const float*)d_in[4];
  const float* qnw = (const float*)d_in[5];
  const float* knw = (const float*)d_in[6];
  float* out = (float*)d_out;

  char* ws = (char*)d_ws;
  unsigned short* Xb   = (unsigned short*)(ws);                 // [4096][2048]
  unsigned short* Wqkb = (unsigned short*)(ws + 16777216);      // [2560][2048]
  unsigned short* Wvb  = (unsigned short*)(ws + 27262976);      // [512][2048]
  unsigned short* Wob  = (unsigned short*)(ws + 29360128);      // [2048][2048]
  unsigned short* QKb  = (unsigned short*)(ws + 37748736);      // [4096][2560]
  unsigned short* VTb  = (unsigned short*)(ws + 58720256);      // [512][4096]
  unsigned short* Obuf = (unsigned short*)(ws + 62914560);      // [4096][2048]
  float* cosT = (float*)(ws + 79691776);                        // [2048][64]
  float* sinT = (float*)(ws + 80216064);

  cast_kernel<<<1024, 256, 0, stream>>>(x, Xb, NTOK * D_DIM);
  cast_kernel<<<1024, 256, 0, stream>>>(wq, Wqkb, D_DIM * D_DIM);
  cast_kernel<<<256, 256, 0, stream>>>(wk, Wqkb + (size_t)D_DIM * D_DIM, 512 * D_DIM);
  cast_kernel<<<256, 256, 0, stream>>>(wv, Wvb, 512 * D_DIM);
  cast_kernel<<<1024, 256, 0, stream>>>(wo, Wob, D_DIM * D_DIM);
  rope_table_kernel<<<512, 256, 0, stream>>>(cosT, sinT);

  // QK projection: [4096][2560]
  dim3 g1(NTOK / 128, NQK / 128);
  gemm_bt_kernel<unsigned short><<<g1, 256, 0, stream>>>(Xb, Wqkb, QKb, NTOK, NQK, D_DIM);

  // V^T directly: VT[dv][token] = sum_k Wv[dv][k] X[token][k]
  dim3 gv(512 / 128, NTOK / 128);
  gemm_bt_kernel<unsigned short><<<gv, 256, 0, stream>>>(Wvb, Xb, VTb, 512, NTOK, D_DIM);

  norm_rope_kernel<<<(NTOK * (H_HEADS + KV_HEADS)) / 4, 256, 0, stream>>>(QKb, qnw, knw, cosT, sinT);

  attn_kernel<<<dim3(SEQ_L / 128, BATCH * H_HEADS), 256, 0, stream>>>(QKb, VTb, Obuf);

  dim3 g2(NTOK / 128, D_DIM / 128);
  gemm_bt_kernel<float><<<g2, 256, 0, stream>>>(Obuf, Wob, out, NTOK, D_DIM, D_DIM);
}

// Round 8
// 294.361 us; speedup vs baseline: 1.6748x; 1.0368x over previous
//
#include <hip/hip_runtime.h>
#include <hip/hip_bf16.h>
#include <stdint.h>
#include <stddef.h>

// Problem constants
#define D_DIM 2048
#define H_HEADS 16
#define KV_HEADS 4
#define HEAD_DIM 128
#define SEQ_L 2048
#define BATCH 2
#define NTOK 4096      // BATCH*SEQ_L
#define NQK 2560       // D + KV_HEADS*HEAD_DIM   (Q + K only; V handled separately)

typedef __attribute__((ext_vector_type(4))) float f32x4;
typedef __attribute__((ext_vector_type(16))) float f32x16;
typedef __attribute__((ext_vector_type(8))) short bf16x8;

__device__ __forceinline__ unsigned short f2bf(float f) {
  __hip_bfloat16 h = __float2bfloat16(f);            // RTNE
  return *reinterpret_cast<unsigned short*>(&h);
}
__device__ __forceinline__ unsigned pack2(float lo, float hi) {
  return (unsigned)f2bf(lo) | ((unsigned)f2bf(hi) << 16);
}
__device__ __forceinline__ float bf2f(unsigned short s) {
  return __uint_as_float(((unsigned int)s) << 16);
}

__device__ __forceinline__ void async_copy16(const void* g, void* l) {
  __builtin_amdgcn_global_load_lds(
      (__attribute__((address_space(1))) void*)(g),
      (__attribute__((address_space(3))) void*)(l),
      16, 0, 0);
}

// ---------------- fused fp32 -> bf16 casts (5 segments, one launch) ----------------
__device__ __forceinline__ void cast_seg(const float* __restrict__ src,
                                         unsigned short* __restrict__ dst,
                                         int n4, int gid, int stride) {
  for (int i = gid; i < n4; i += stride) {
    float4 v = *reinterpret_cast<const float4*>(src + i * 4);
    uint2 o;
    o.x = pack2(v.x, v.y);
    o.y = pack2(v.z, v.w);
    *reinterpret_cast<uint2*>(dst + i * 4) = o;
  }
}

__global__ __launch_bounds__(256) void fused_cast_kernel(
    const float* __restrict__ s0, const float* __restrict__ s1,
    const float* __restrict__ s2, const float* __restrict__ s3,
    const float* __restrict__ s4,
    unsigned short* __restrict__ d0, unsigned short* __restrict__ d1,
    unsigned short* __restrict__ d2, unsigned short* __restrict__ d3,
    unsigned short* __restrict__ d4) {
  int gid = blockIdx.x * blockDim.x + threadIdx.x;
  int stride = gridDim.x * blockDim.x;
  cast_seg(s0, d0, (NTOK * D_DIM) / 4, gid, stride);          // x
  cast_seg(s1, d1, (D_DIM * D_DIM) / 4, gid, stride);         // wq
  cast_seg(s2, d2, (512 * D_DIM) / 4, gid, stride);           // wk
  cast_seg(s3, d3, (512 * D_DIM) / 4, gid, stride);           // wv
  cast_seg(s4, d4, (D_DIM * D_DIM) / 4, gid, stride);         // wo
}

// ---------------- RoPE table ----------------
__global__ __launch_bounds__(256) void rope_table_kernel(float* __restrict__ cosT,
                                                         float* __restrict__ sinT) {
  int i = blockIdx.x * blockDim.x + threadIdx.x;  // l*64 + p
  if (i >= SEQ_L * 64) return;
  int p = i & 63;
  float l = (float)(i >> 6);
  float inv = powf(10000.0f, -(float)p / 64.0f);
  float ang = l * inv;
  cosT[i] = cosf(ang);
  sinT[i] = sinf(ang);
}

// ---------------- GEMM: C[M,N] = A[M,K] * B[N,K]^T  (bf16 in, OutT out) ----------------
__device__ __forceinline__ void store_out(unsigned short* p, float v) { *p = f2bf(v); }
__device__ __forceinline__ void store_out(float* p, float v) { *p = v; }

template <typename OutT>
__global__ __launch_bounds__(256) void gemm_bt_kernel(const unsigned short* __restrict__ A,
                                                      const unsigned short* __restrict__ B,
                                                      OutT* __restrict__ C,
                                                      int M, int N, int K) {
  __shared__ unsigned short Alds[128 * 32];
  __shared__ unsigned short Blds[128 * 32];
  const int tid = threadIdx.x;
  const int wave = tid >> 6;
  const int lane = tid & 63;
  const int l15 = lane & 15;
  const int l4 = lane >> 4;

  // XCD-aware bijective swizzle (T1): nwg divisible by 8 for all our grids
  const int nwg = gridDim.x * gridDim.y;
  const int orig = blockIdx.y * gridDim.x + blockIdx.x;
  const int cpx = nwg >> 3;
  const int swz = (orig & 7) * cpx + (orig >> 3);
  const int m0 = (swz % gridDim.x) * 128;
  const int n0 = (swz / gridDim.x) * 128;

  const int wm = (wave >> 1) * 64;
  const int wn = (wave & 1) * 64;

  f32x4 acc[4][4] = {};

  const int soff0 = wave * 1024 + lane * 16;  // bytes within 8KB tile

  for (int kt = 0; kt < K; kt += 32) {
#pragma unroll
    for (int inst = 0; inst < 2; ++inst) {
      int off = soff0 + inst * 4096;
      int row = off >> 6;    // 64 bytes (32 bf16) per LDS row
      int colb = off & 63;
      const char* ga = (const char*)(A + (size_t)(m0 + row) * K + kt) + colb;
      async_copy16(ga, (char*)Alds + off);
      const char* gb = (const char*)(B + (size_t)(n0 + row) * K + kt) + colb;
      async_copy16(gb, (char*)Blds + off);
    }
    __syncthreads();
    bf16x8 af[4], bfr[4];
#pragma unroll
    for (int i = 0; i < 4; ++i)
      af[i] = *reinterpret_cast<const bf16x8*>(Alds + (wm + i * 16 + l15) * 32 + l4 * 8);
#pragma unroll
    for (int j = 0; j < 4; ++j)
      bfr[j] = *reinterpret_cast<const bf16x8*>(Blds + (wn + j * 16 + l15) * 32 + l4 * 8);
#pragma unroll
    for (int i = 0; i < 4; ++i)
#pragma unroll
      for (int j = 0; j < 4; ++j)
        acc[i][j] = __builtin_amdgcn_mfma_f32_16x16x32_bf16(af[i], bfr[j], acc[i][j], 0, 0, 0);
    __syncthreads();
  }

#pragma unroll
  for (int i = 0; i < 4; ++i)
#pragma unroll
    for (int j = 0; j < 4; ++j) {
      int col = n0 + wn + j * 16 + l15;
#pragma unroll
      for (int r = 0; r < 4; ++r) {
        int row = m0 + wm + i * 16 + l4 * 4 + r;
        store_out(C + (size_t)row * N + col, acc[i][j][r]);
      }
    }
}

// ---------------- RMSNorm + RoPE (in-place on QK buffer, stride NQK) ----------------
// Also folds the attention scale 1/sqrt(HD) into Q rows.
__global__ __launch_bounds__(256) void norm_rope_kernel(unsigned short* __restrict__ qk,
                                                        const float* __restrict__ qw,
                                                        const float* __restrict__ kw,
                                                        const float* __restrict__ cosT,
                                                        const float* __restrict__ sinT) {
  int wid = (blockIdx.x * blockDim.x + threadIdx.x) >> 6;  // global wave id
  int lane = threadIdx.x & 63;
  unsigned short* rowp;
  const float* w;
  int m;
  float sc;
  if (wid < NTOK * H_HEADS) {
    m = wid >> 4;
    int hh = wid & 15;
    rowp = qk + (size_t)m * NQK + hh * HEAD_DIM;
    w = qw;
    sc = 0.08838834764831845f;   // fold 1/sqrt(128) into Q
  } else {
    int r2 = wid - NTOK * H_HEADS;
    m = r2 >> 2;
    int kvh = r2 & 3;
    rowp = qk + (size_t)m * NQK + D_DIM + kvh * HEAD_DIM;
    w = kw;
    sc = 1.0f;
  }
  int l = m & (SEQ_L - 1);
  unsigned int pair = *reinterpret_cast<const unsigned int*>(rowp + lane * 2);
  float e = bf2f((unsigned short)(pair & 0xffffu));
  float o = bf2f((unsigned short)(pair >> 16));
  float ss = e * e + o * o;
#pragma unroll
  for (int off = 1; off < 64; off <<= 1) ss += __shfl_xor(ss, off);
  float rsn = rsqrtf(ss * (1.0f / 128.0f) + 1e-6f) * sc;
  float we = w[lane * 2], wo_ = w[lane * 2 + 1];
  float c = cosT[l * 64 + lane], s = sinT[l * 64 + lane];
  float xe = e * rsn * we, xo = o * rsn * wo_;
  float re = xe * c - xo * s;
  float ro = xe * s + xo * c;
  *reinterpret_cast<unsigned int*>(rowp + lane * 2) = pack2(re, ro);
}

// ---------------- Flash attention v6: swapped-QK 32x32, KVBLK=64, dbuf, PAIRED ----------------
// QBLK=64, 2 waves/block (128 thr). Block j handles q-tiles {j, 31-j}:
// work = (j+1)+(32-j) = 33 KV-tiles for EVERY block -> uniform makespan.
__global__ __launch_bounds__(128) void attn_kernel(const unsigned short* __restrict__ qk,
                                                   const unsigned short* __restrict__ vt,
                                                   unsigned short* __restrict__ obuf) {
  __shared__ unsigned short Kl[2][64 * 128];   // [key][d], XOR-swizzled rows (256B)
  __shared__ unsigned short Vl[2][128 * 64];   // [d][key], XOR-swizzled rows (128B)
  __shared__ float invl[64];

  const int tid = threadIdx.x;
  const int w = tid >> 6, lane = tid & 63;     // w in {0,1}
  const int l31 = lane & 31, hi = lane >> 5;
  const int job = blockIdx.x;                  // 0..15
  const int bh = blockIdx.y;
  const int b = bh >> 4, h = bh & 15, kvh = h >> 2;

  const unsigned short* Kg = qk + (size_t)(b * SEQ_L) * NQK + D_DIM + kvh * HEAD_DIM;
  const unsigned short* Vg = vt + (size_t)(kvh * HEAD_DIM) * NTOK + b * SEQ_L;

  auto stage = [&](int bb, int kt) {
#pragma unroll
    for (int i = 0; i < 8; ++i) {
      int o = (i * 128 + tid) * 16;   // byte offset of this thread's 16B slot
      {  // K tile: [64 rows][256B], swz: byte ^= ((row&7)<<4)
        int row = o >> 8;
        int scb = (o & 255) ^ ((row & 7) << 4);
        const char* src = (const char*)(Kg + (size_t)(kt * 64 + row) * NQK) + scb;
        async_copy16(src, (char*)(&Kl[bb][0]) + o);
      }
      {  // V^T tile: [128 rows][128B], swz: byte ^= ((d&7)<<4)
        int d = o >> 7;
        int skb = (o & 127) ^ ((d & 7) << 4);
        const char* src = (const char*)(Vg + (size_t)d * NTOK + kt * 64) + skb;
        async_copy16(src, (char*)(&Vl[bb][0]) + o);
      }
    }
  };

#pragma unroll 1
  for (int jj = 0; jj < 2; ++jj) {
    const int jt = jj ? (31 - job) : job;
    const int q0 = jt * 64;
    const int ntiles = jt + 1;

    const unsigned short* Qg =
        qk + (size_t)(b * SEQ_L + q0 + w * 32 + l31) * NQK + h * HEAD_DIM;
    bf16x8 qf[8];
#pragma unroll
    for (int kk = 0; kk < 8; ++kk)
      qf[kk] = *reinterpret_cast<const bf16x8*>(Qg + kk * 16 + hi * 8);

    f32x16 accO[4] = {};
    float m_run = -1e30f, l_run = 0.0f;

    const int qmin_w = q0 + w * 32;
    const int qg = qmin_w + l31;

    stage(0, 0);
    asm volatile("s_waitcnt vmcnt(0)" ::: "memory");
    __syncthreads();

    int buf = 0;
    for (int kt = 0; kt < ntiles; ++kt) {
      if (kt + 1 < ntiles) stage(buf ^ 1, kt + 1);

      {
        // ---- QK^T: S^T[key][q], two 32-key sub-tiles ----
        f32x16 st[2] = {};
        __builtin_amdgcn_s_setprio(1);
#pragma unroll
        for (int stile = 0; stile < 2; ++stile) {
#pragma unroll
          for (int kk = 0; kk < 8; ++kk) {
            int row = stile * 32 + l31;
            int off = (row << 8) + (((kk << 5) + (hi << 4)) ^ ((l31 & 7) << 4));
            bf16x8 kf = *reinterpret_cast<const bf16x8*>((const char*)(&Kl[buf][0]) + off);
            st[stile] = __builtin_amdgcn_mfma_f32_32x32x16_bf16(kf, qf[kk], st[stile], 0, 0, 0);
          }
        }
        __builtin_amdgcn_s_setprio(0);

        // ---- mask + per-lane online softmax (scale pre-folded into Q) ----
        const bool need_mask = (kt * 64 + 63 > qmin_w);
        float tmax = -1e30f;
#pragma unroll
        for (int stile = 0; stile < 2; ++stile)
#pragma unroll
          for (int r = 0; r < 16; ++r) {
            float s = st[stile][r];
            if (need_mask) {
              int key = kt * 64 + stile * 32 + (r & 3) + ((r >> 2) << 3) + (hi << 2);
              if (key > qg) s = -1e30f;
            }
            st[stile][r] = s;
            tmax = fmaxf(tmax, s);
          }
        tmax = fmaxf(tmax, __shfl_xor(tmax, 32));

        // ---- defer-max (T13): only rescale when the running max grew > THR ----
        if (!__all(tmax - m_run <= 8.0f)) {
          float mnew = fmaxf(m_run, tmax);
          float corr = __expf(m_run - mnew);
          m_run = mnew;
          l_run *= corr;
          float corrq[16];
#pragma unroll
          for (int r = 0; r < 16; ++r) {
            int qi = (r & 3) + ((r >> 2) << 3) + (hi << 2);
            corrq[r] = __shfl(corr, qi);
          }
#pragma unroll
          for (int dt = 0; dt < 4; ++dt)
#pragma unroll
            for (int r = 0; r < 16; ++r) accO[dt][r] *= corrq[r];
        }

        float rsum = 0.0f;
#pragma unroll
        for (int stile = 0; stile < 2; ++stile)
#pragma unroll
          for (int r = 0; r < 16; ++r) {
            float pe = __expf(st[stile][r] - m_run);
            st[stile][r] = pe;
            rsum += pe;
          }
        rsum += __shfl_xor(rsum, 32);
        l_run += rsum;

        // ---- P -> bf16 A-fragments: pack + half-exchange (shfl_xor + select) ----
        bf16x8 pa[2][2];
#pragma unroll
        for (int stile = 0; stile < 2; ++stile)
#pragma unroll
          for (int kc = 0; kc < 2; ++kc) {
            int rb = kc * 8;
            unsigned x0 = pack2(st[stile][rb + 0], st[stile][rb + 1]);
            unsigned y0 = pack2(st[stile][rb + 4], st[stile][rb + 5]);
            unsigned x1 = pack2(st[stile][rb + 2], st[stile][rb + 3]);
            unsigned y1 = pack2(st[stile][rb + 6], st[stile][rb + 7]);
            unsigned x0s = (unsigned)__shfl_xor((int)x0, 32);
            unsigned y0s = (unsigned)__shfl_xor((int)y0, 32);
            unsigned x1s = (unsigned)__shfl_xor((int)x1, 32);
            unsigned y1s = (unsigned)__shfl_xor((int)y1, 32);
            unsigned w0 = hi ? y0s : x0;   // keys hi*8 + {0,1}
            unsigned w2 = hi ? y0 : x0s;   // keys hi*8 + {4,5}
            unsigned w1 = hi ? y1s : x1;   // keys hi*8 + {2,3}
            unsigned w3 = hi ? y1 : x1s;   // keys hi*8 + {6,7}
            union { bf16x8 v; unsigned u[4]; } uu;
            uu.u[0] = w0; uu.u[1] = w1; uu.u[2] = w2; uu.u[3] = w3;
            pa[stile][kc] = uu.v;
          }

        // ---- PV: O[q][d] += P * V ----
        __builtin_amdgcn_s_setprio(1);
#pragma unroll
        for (int dt = 0; dt < 4; ++dt) {
          int drow = dt * 32 + l31;
#pragma unroll
          for (int stile = 0; stile < 2; ++stile)
#pragma unroll
            for (int kc = 0; kc < 2; ++kc) {
              int off = (drow << 7) + (((stile << 6) + (kc << 5) + (hi << 4)) ^ ((l31 & 7) << 4));
              bf16x8 vf = *reinterpret_cast<const bf16x8*>((const char*)(&Vl[buf][0]) + off);
              accO[dt] = __builtin_amdgcn_mfma_f32_32x32x16_bf16(pa[stile][kc], vf, accO[dt], 0, 0, 0);
            }
        }
        __builtin_amdgcn_s_setprio(0);
      }

      asm volatile("s_waitcnt vmcnt(0)" ::: "memory");
      __syncthreads();
      buf ^= 1;
    }

    // ---- epilogue: O /= l (1/l redistributed via tiny LDS table) ----
    if (hi == 0) invl[w * 32 + l31] = 1.0f / l_run;
    __syncthreads();
#pragma unroll
    for (int dt = 0; dt < 4; ++dt)
#pragma unroll
      for (int r = 0; r < 16; ++r) {
        int qrow = (r & 3) + ((r >> 2) << 3) + (hi << 2);
        float val = accO[dt][r] * invl[w * 32 + qrow];
        int tok = b * SEQ_L + q0 + w * 32 + qrow;
        obuf[(size_t)tok * D_DIM + h * HEAD_DIM + dt * 32 + l31] = f2bf(val);
      }
    __syncthreads();   // protect invl + LDS reuse before next job
  }
}

// ---------------- launcher ----------------
extern "C" void kernel_launch(void* const* d_in, const int* in_sizes, int n_in,
                              void* d_out, int out_size, void* d_ws, size_t ws_size,
                              hipStream_t stream) {
  const float* x   = (const float*)d_in[0];
  const float* wq  = (const float*)d_in[1];
  const float* wk  = (const float*)d_in[2];
  const float* wv  = (const float*)d_in[3];
  const float* wo  = (const float*)d_in[4];
  const float* qnw = (const float*)d_in[5];
  const float* knw = (const float*)d_in[6];
  float* out = (float*)d_out;

  char* ws = (char*)d_ws;
  unsigned short* Xb   = (unsigned short*)(ws);                 // [4096][2048]
  unsigned short* Wqkb = (unsigned short*)(ws + 16777216);      // [2560][2048]
  unsigned short* Wvb  = (unsigned short*)(ws + 27262976);      // [512][2048]
  unsigned short* Wob  = (unsigned short*)(ws + 29360128);      // [2048][2048]
  unsigned short* QKb  = (unsigned short*)(ws + 37748736);      // [4096][2560]
  unsigned short* VTb  = (unsigned short*)(ws + 58720256);      // [512][4096]
  unsigned short* Obuf = (unsigned short*)(ws + 62914560);      // [4096][2048]
  float* cosT = (float*)(ws + 79691776);                        // [2048][64]
  float* sinT = (float*)(ws + 80216064);

  fused_cast_kernel<<<1024, 256, 0, stream>>>(
      x, wq, wk, wv, wo,
      Xb, Wqkb, Wqkb + (size_t)D_DIM * D_DIM, Wvb, Wob);
  rope_table_kernel<<<512, 256, 0, stream>>>(cosT, sinT);

  // QK projection: [4096][2560]
  dim3 g1(NTOK / 128, NQK / 128);
  gemm_bt_kernel<unsigned short><<<g1, 256, 0, stream>>>(Xb, Wqkb, QKb, NTOK, NQK, D_DIM);

  // V^T directly: VT[dv][token] = sum_k Wv[dv][k] X[token][k]
  dim3 gv(512 / 128, NTOK / 128);
  gemm_bt_kernel<unsigned short><<<gv, 256, 0, stream>>>(Wvb, Xb, VTb, 512, NTOK, D_DIM);

  norm_rope_kernel<<<(NTOK * (H_HEADS + KV_HEADS)) / 4, 256, 0, stream>>>(QKb, qnw, knw, cosT, sinT);

  attn_kernel<<<dim3(16, BATCH * H_HEADS), 128, 0, stream>>>(QKb, VTb, Obuf);

  dim3 g2(NTOK / 128, D_DIM / 128);
  gemm_bt_kernel<float><<<g2, 256, 0, stream>>>(Obuf, Wob, out, NTOK, D_DIM, D_DIM);
}

// Round 9
// 260.321 us; speedup vs baseline: 1.8938x; 1.1308x over previous
//
#include <hip/hip_runtime.h>
#include <hip/hip_bf16.h>
#include <stdint.h>
#include <stddef.h>

// Problem constants
#define D_DIM 2048
#define H_HEADS 16
#define KV_HEADS 4
#define HEAD_DIM 128
#define SEQ_L 2048
#define BATCH 2
#define NTOK 4096      // BATCH*SEQ_L
#define NQK 2560       // D + KV_HEADS*HEAD_DIM (Q+K rows; V handled via transposed path)
#define NQKV 3072      // Q+K+V rows in the merged projection

typedef __attribute__((ext_vector_type(4))) float f32x4;
typedef __attribute__((ext_vector_type(16))) float f32x16;
typedef __attribute__((ext_vector_type(8))) short bf16x8;

__device__ __forceinline__ unsigned short f2bf(float f) {
  __hip_bfloat16 h = __float2bfloat16(f);            // RTNE
  return *reinterpret_cast<unsigned short*>(&h);
}
__device__ __forceinline__ unsigned pack2(float lo, float hi) {
  return (unsigned)f2bf(lo) | ((unsigned)f2bf(hi) << 16);
}
__device__ __forceinline__ float bf2f(unsigned short s) {
  return __uint_as_float(((unsigned int)s) << 16);
}

__device__ __forceinline__ void async_copy16(const void* g, void* l) {
  __builtin_amdgcn_global_load_lds(
      (__attribute__((address_space(1))) void*)(g),
      (__attribute__((address_space(3))) void*)(l),
      16, 0, 0);
}

// ---------------- fused fp32 -> bf16 casts (5 segments, one launch) ----------------
__device__ __forceinline__ void cast_seg(const float* __restrict__ src,
                                         unsigned short* __restrict__ dst,
                                         int n4, int gid, int stride) {
  for (int i = gid; i < n4; i += stride) {
    float4 v = *reinterpret_cast<const float4*>(src + i * 4);
    uint2 o;
    o.x = pack2(v.x, v.y);
    o.y = pack2(v.z, v.w);
    *reinterpret_cast<uint2*>(dst + i * 4) = o;
  }
}

__global__ __launch_bounds__(256) void fused_cast_kernel(
    const float* __restrict__ s0, const float* __restrict__ s1,
    const float* __restrict__ s2, const float* __restrict__ s3,
    const float* __restrict__ s4,
    unsigned short* __restrict__ d0, unsigned short* __restrict__ d1,
    unsigned short* __restrict__ d2, unsigned short* __restrict__ d3,
    unsigned short* __restrict__ d4) {
  int gid = blockIdx.x * blockDim.x + threadIdx.x;
  int stride = gridDim.x * blockDim.x;
  cast_seg(s0, d0, (NTOK * D_DIM) / 4, gid, stride);          // x
  cast_seg(s1, d1, (D_DIM * D_DIM) / 4, gid, stride);         // wq
  cast_seg(s2, d2, (512 * D_DIM) / 4, gid, stride);           // wk
  cast_seg(s3, d3, (512 * D_DIM) / 4, gid, stride);           // wv
  cast_seg(s4, d4, (D_DIM * D_DIM) / 4, gid, stride);         // wo
}

// ---------------- RoPE table ----------------
__global__ __launch_bounds__(256) void rope_table_kernel(float* __restrict__ cosT,
                                                         float* __restrict__ sinT) {
  int i = blockIdx.x * blockDim.x + threadIdx.x;  // l*64 + p
  if (i >= SEQ_L * 64) return;
  int p = i & 63;
  float l = (float)(i >> 6);
  float inv = powf(10000.0f, -(float)p / 64.0f);
  float ang = l * inv;
  cosT[i] = cosf(ang);
  sinT[i] = sinf(ang);
}

// ---------------- GEMM: C[M,N] = A[M,K] * B[N,K]^T  (bf16 in, OutT out) ----------------
// VSPLIT: B rows [0,NQK) -> C (stride NQK); rows [NQK,NQKV) -> vt transposed
// ([dv][token], contiguous ushort4 per lane since acc rows are consecutive tokens).
__device__ __forceinline__ void store_out(unsigned short* p, float v) { *p = f2bf(v); }
__device__ __forceinline__ void store_out(float* p, float v) { *p = v; }

template <typename OutT, bool VSPLIT>
__global__ __launch_bounds__(256) void gemm_bt_kernel(const unsigned short* __restrict__ A,
                                                      const unsigned short* __restrict__ B,
                                                      OutT* __restrict__ C,
                                                      unsigned short* __restrict__ vt,
                                                      int M, int N, int K) {
  __shared__ unsigned short Alds[128 * 32];
  __shared__ unsigned short Blds[128 * 32];
  const int tid = threadIdx.x;
  const int wave = tid >> 6;
  const int lane = tid & 63;
  const int l15 = lane & 15;
  const int l4 = lane >> 4;

  // XCD-aware bijective swizzle (T1): nwg divisible by 8 for all our grids
  const int nwg = gridDim.x * gridDim.y;
  const int orig = blockIdx.y * gridDim.x + blockIdx.x;
  const int cpx = nwg >> 3;
  const int swz = (orig & 7) * cpx + (orig >> 3);
  const int m0 = (swz % gridDim.x) * 128;
  const int n0 = (swz / gridDim.x) * 128;

  const int wm = (wave >> 1) * 64;
  const int wn = (wave & 1) * 64;

  f32x4 acc[4][4] = {};

  const int soff0 = wave * 1024 + lane * 16;  // bytes within 8KB tile

  for (int kt = 0; kt < K; kt += 32) {
#pragma unroll
    for (int inst = 0; inst < 2; ++inst) {
      int off = soff0 + inst * 4096;
      int row = off >> 6;    // 64 bytes (32 bf16) per LDS row
      int colb = off & 63;
      const char* ga = (const char*)(A + (size_t)(m0 + row) * K + kt) + colb;
      async_copy16(ga, (char*)Alds + off);
      const char* gb = (const char*)(B + (size_t)(n0 + row) * K + kt) + colb;
      async_copy16(gb, (char*)Blds + off);
    }
    __syncthreads();
    bf16x8 af[4], bfr[4];
#pragma unroll
    for (int i = 0; i < 4; ++i)
      af[i] = *reinterpret_cast<const bf16x8*>(Alds + (wm + i * 16 + l15) * 32 + l4 * 8);
#pragma unroll
    for (int j = 0; j < 4; ++j)
      bfr[j] = *reinterpret_cast<const bf16x8*>(Blds + (wn + j * 16 + l15) * 32 + l4 * 8);
#pragma unroll
    for (int i = 0; i < 4; ++i)
#pragma unroll
      for (int j = 0; j < 4; ++j)
        acc[i][j] = __builtin_amdgcn_mfma_f32_16x16x32_bf16(af[i], bfr[j], acc[i][j], 0, 0, 0);
    __syncthreads();
  }

  if (VSPLIT && n0 >= NQK) {
    // V block: write transposed into vt[dv][token]
#pragma unroll
    for (int i = 0; i < 4; ++i)
#pragma unroll
      for (int j = 0; j < 4; ++j) {
        int vrow = n0 + wn + j * 16 + l15 - NQK;
        int tok0 = m0 + wm + i * 16 + l4 * 4;
        ushort4 pk;
        pk.x = f2bf(acc[i][j][0]);
        pk.y = f2bf(acc[i][j][1]);
        pk.z = f2bf(acc[i][j][2]);
        pk.w = f2bf(acc[i][j][3]);
        *reinterpret_cast<ushort4*>(vt + (size_t)vrow * NTOK + tok0) = pk;
      }
    return;
  }

  const int cstride = VSPLIT ? NQK : N;
#pragma unroll
  for (int i = 0; i < 4; ++i)
#pragma unroll
    for (int j = 0; j < 4; ++j) {
      int col = n0 + wn + j * 16 + l15;
#pragma unroll
      for (int r = 0; r < 4; ++r) {
        int row = m0 + wm + i * 16 + l4 * 4 + r;
        store_out(C + (size_t)row * cstride + col, acc[i][j][r]);
      }
    }
}

// ---------------- RMSNorm + RoPE (in-place on QK buffer, stride NQK) ----------------
// Also folds the attention scale 1/sqrt(HD) into Q rows.
__global__ __launch_bounds__(256) void norm_rope_kernel(unsigned short* __restrict__ qk,
                                                        const float* __restrict__ qw,
                                                        const float* __restrict__ kw,
                                                        const float* __restrict__ cosT,
                                                        const float* __restrict__ sinT) {
  int wid = (blockIdx.x * blockDim.x + threadIdx.x) >> 6;  // global wave id
  int lane = threadIdx.x & 63;
  unsigned short* rowp;
  const float* w;
  int m;
  float sc;
  if (wid < NTOK * H_HEADS) {
    m = wid >> 4;
    int hh = wid & 15;
    rowp = qk + (size_t)m * NQK + hh * HEAD_DIM;
    w = qw;
    sc = 0.08838834764831845f;   // fold 1/sqrt(128) into Q
  } else {
    int r2 = wid - NTOK * H_HEADS;
    m = r2 >> 2;
    int kvh = r2 & 3;
    rowp = qk + (size_t)m * NQK + D_DIM + kvh * HEAD_DIM;
    w = kw;
    sc = 1.0f;
  }
  int l = m & (SEQ_L - 1);
  unsigned int pair = *reinterpret_cast<const unsigned int*>(rowp + lane * 2);
  float e = bf2f((unsigned short)(pair & 0xffffu));
  float o = bf2f((unsigned short)(pair >> 16));
  float ss = e * e + o * o;
#pragma unroll
  for (int off = 1; off < 64; off <<= 1) ss += __shfl_xor(ss, off);
  float rsn = rsqrtf(ss * (1.0f / 128.0f) + 1e-6f) * sc;
  float we = w[lane * 2], wo_ = w[lane * 2 + 1];
  float c = cosT[l * 64 + lane], s = sinT[l * 64 + lane];
  float xe = e * rsn * we, xo = o * rsn * wo_;
  float re = xe * c - xo * s;
  float ro = xe * s + xo * c;
  *reinterpret_cast<unsigned int*>(rowp + lane * 2) = pack2(re, ro);
}

// ---------------- Flash attention v5 (R7 config): swapped-QK 32x32, KVBLK=64, dbuf ----------------
// 4 waves / 256 thr, 128 q rows per block, LPT launch order. 2 blocks/CU, 8 waves/CU.
__global__ __launch_bounds__(256, 2) void attn_kernel(const unsigned short* __restrict__ qk,
                                                      const unsigned short* __restrict__ vt,
                                                      unsigned short* __restrict__ obuf) {
  __shared__ unsigned short Kl[2][64 * 128];   // [key][d], XOR-swizzled rows (256B)
  __shared__ unsigned short Vl[2][128 * 64];   // [d][key], XOR-swizzled rows (128B)
  __shared__ float invl[128];

  const int tid = threadIdx.x;
  const int w = tid >> 6, lane = tid & 63;
  const int l31 = lane & 31, hi = lane >> 5;
  const int qt = gridDim.x - 1 - blockIdx.x;   // longest-first (LPT)
  const int q0 = qt * 128;
  const int bh = blockIdx.y;
  const int b = bh >> 4, h = bh & 15, kvh = h >> 2;

  const unsigned short* Qg = qk + (size_t)(b * SEQ_L + q0 + w * 32 + l31) * NQK + h * HEAD_DIM;
  const unsigned short* Kg = qk + (size_t)(b * SEQ_L) * NQK + D_DIM + kvh * HEAD_DIM;
  const unsigned short* Vg = vt + (size_t)(kvh * HEAD_DIM) * NTOK + b * SEQ_L;

  // Q fragments in registers: qf[kk] = Q[q=l31][kk*16 + hi*8 .. +7]
  bf16x8 qf[8];
#pragma unroll
  for (int kk = 0; kk < 8; ++kk)
    qf[kk] = *reinterpret_cast<const bf16x8*>(Qg + kk * 16 + hi * 8);

  f32x16 accO[4] = {};
  float m_run = -1e30f, l_run = 0.0f;

  const int qmin_w = q0 + w * 32;
  const int qmax_w = qmin_w + 31;
  const int qg = qmin_w + l31;
  const int ntiles = (q0 + 128) >> 6;

  auto stage = [&](int bb, int kt) {
#pragma unroll
    for (int i = 0; i < 4; ++i) {
      int o = (i * 256 + tid) * 16;   // byte offset of this thread's 16B slot
      {  // K tile: [64 rows][256B], swz: byte ^= ((row&7)<<4)
        int row = o >> 8;
        int scb = (o & 255) ^ ((row & 7) << 4);
        const char* src = (const char*)(Kg + (size_t)(kt * 64 + row) * NQK) + scb;
        async_copy16(src, (char*)(&Kl[bb][0]) + o);
      }
      {  // V^T tile: [128 rows][128B], swz: byte ^= ((d&7)<<4)
        int d = o >> 7;
        int skb = (o & 127) ^ ((d & 7) << 4);
        const char* src = (const char*)(Vg + (size_t)d * NTOK + kt * 64) + skb;
        async_copy16(src, (char*)(&Vl[bb][0]) + o);
      }
    }
  };

  stage(0, 0);
  asm volatile("s_waitcnt vmcnt(0)" ::: "memory");
  __syncthreads();

  int buf = 0;
  for (int kt = 0; kt < ntiles; ++kt) {
    if (kt + 1 < ntiles) stage(buf ^ 1, kt + 1);

    if (kt * 64 <= qmax_w) {   // wave-uniform: skip fully-masked tiles
      // ---- QK^T: S^T[key][q], two 32-key sub-tiles ----
      f32x16 st[2] = {};
      __builtin_amdgcn_s_setprio(1);
#pragma unroll
      for (int stile = 0; stile < 2; ++stile) {
#pragma unroll
        for (int kk = 0; kk < 8; ++kk) {
          int row = stile * 32 + l31;
          int off = (row << 8) + (((kk << 5) + (hi << 4)) ^ ((l31 & 7) << 4));
          bf16x8 kf = *reinterpret_cast<const bf16x8*>((const char*)(&Kl[buf][0]) + off);
          st[stile] = __builtin_amdgcn_mfma_f32_32x32x16_bf16(kf, qf[kk], st[stile], 0, 0, 0);
        }
      }
      __builtin_amdgcn_s_setprio(0);

      // ---- mask + per-lane online softmax (scale pre-folded into Q) ----
      const bool need_mask = (kt * 64 + 63 > qmin_w);
      float tmax = -1e30f;
#pragma unroll
      for (int stile = 0; stile < 2; ++stile)
#pragma unroll
        for (int r = 0; r < 16; ++r) {
          float s = st[stile][r];
          if (need_mask) {
            int key = kt * 64 + stile * 32 + (r & 3) + ((r >> 2) << 3) + (hi << 2);
            if (key > qg) s = -1e30f;
          }
          st[stile][r] = s;
          tmax = fmaxf(tmax, s);
        }
      tmax = fmaxf(tmax, __shfl_xor(tmax, 32));

      // ---- defer-max (T13): only rescale when the running max grew > THR ----
      if (!__all(tmax - m_run <= 8.0f)) {
        float mnew = fmaxf(m_run, tmax);
        float corr = __expf(m_run - mnew);
        m_run = mnew;
        l_run *= corr;
        float corrq[16];
#pragma unroll
        for (int r = 0; r < 16; ++r) {
          int qi = (r & 3) + ((r >> 2) << 3) + (hi << 2);
          corrq[r] = __shfl(corr, qi);
        }
#pragma unroll
        for (int dt = 0; dt < 4; ++dt)
#pragma unroll
          for (int r = 0; r < 16; ++r) accO[dt][r] *= corrq[r];
      }

      float rsum = 0.0f;
#pragma unroll
      for (int stile = 0; stile < 2; ++stile)
#pragma unroll
        for (int r = 0; r < 16; ++r) {
          float pe = __expf(st[stile][r] - m_run);
          st[stile][r] = pe;
          rsum += pe;
        }
      rsum += __shfl_xor(rsum, 32);
      l_run += rsum;

      // ---- P -> bf16 A-fragments: pack + half-exchange (shfl_xor + select) ----
      bf16x8 pa[2][2];
#pragma unroll
      for (int stile = 0; stile < 2; ++stile)
#pragma unroll
        for (int kc = 0; kc < 2; ++kc) {
          int rb = kc * 8;
          unsigned x0 = pack2(st[stile][rb + 0], st[stile][rb + 1]);
          unsigned y0 = pack2(st[stile][rb + 4], st[stile][rb + 5]);
          unsigned x1 = pack2(st[stile][rb + 2], st[stile][rb + 3]);
          unsigned y1 = pack2(st[stile][rb + 6], st[stile][rb + 7]);
          unsigned x0s = (unsigned)__shfl_xor((int)x0, 32);
          unsigned y0s = (unsigned)__shfl_xor((int)y0, 32);
          unsigned x1s = (unsigned)__shfl_xor((int)x1, 32);
          unsigned y1s = (unsigned)__shfl_xor((int)y1, 32);
          unsigned w0 = hi ? y0s : x0;   // keys hi*8 + {0,1}
          unsigned w2 = hi ? y0 : x0s;   // keys hi*8 + {4,5}
          unsigned w1 = hi ? y1s : x1;   // keys hi*8 + {2,3}
          unsigned w3 = hi ? y1 : x1s;   // keys hi*8 + {6,7}
          union { bf16x8 v; unsigned u[4]; } uu;
          uu.u[0] = w0; uu.u[1] = w1; uu.u[2] = w2; uu.u[3] = w3;
          pa[stile][kc] = uu.v;
        }

      // ---- PV: O[q][d] += P * V ----
      __builtin_amdgcn_s_setprio(1);
#pragma unroll
      for (int dt = 0; dt < 4; ++dt) {
        int drow = dt * 32 + l31;
#pragma unroll
        for (int stile = 0; stile < 2; ++stile)
#pragma unroll
          for (int kc = 0; kc < 2; ++kc) {
            int off = (drow << 7) + (((stile << 6) + (kc << 5) + (hi << 4)) ^ ((l31 & 7) << 4));
            bf16x8 vf = *reinterpret_cast<const bf16x8*>((const char*)(&Vl[buf][0]) + off);
            accO[dt] = __builtin_amdgcn_mfma_f32_32x32x16_bf16(pa[stile][kc], vf, accO[dt], 0, 0, 0);
          }
      }
      __builtin_amdgcn_s_setprio(0);
    }

    asm volatile("s_waitcnt vmcnt(0)" ::: "memory");
    __syncthreads();
    buf ^= 1;
  }

  // ---- epilogue: O /= l (1/l redistributed via tiny LDS table) ----
  if (hi == 0) invl[w * 32 + l31] = 1.0f / l_run;
  __syncthreads();
#pragma unroll
  for (int dt = 0; dt < 4; ++dt)
#pragma unroll
    for (int r = 0; r < 16; ++r) {
      int qrow = (r & 3) + ((r >> 2) << 3) + (hi << 2);
      float val = accO[dt][r] * invl[w * 32 + qrow];
      int tok = b * SEQ_L + q0 + w * 32 + qrow;
      obuf[(size_t)tok * D_DIM + h * HEAD_DIM + dt * 32 + l31] = f2bf(val);
    }
}

// ---------------- launcher ----------------
extern "C" void kernel_launch(void* const* d_in, const int* in_sizes, int n_in,
                              void* d_out, int out_size, void* d_ws, size_t ws_size,
                              hipStream_t stream) {
  const float* x   = (const float*)d_in[0];
  const float* wq  = (const float*)d_in[1];
  const float* wk  = (const float*)d_in[2];
  const float* wv  = (const float*)d_in[3];
  const float* wo  = (const float*)d_in[4];
  const float* qnw = (const float*)d_in[5];
  const float* knw = (const float*)d_in[6];
  float* out = (float*)d_out;

  char* ws = (char*)d_ws;
  unsigned short* Xb    = (unsigned short*)(ws);                 // [4096][2048]
  unsigned short* Wqkvb = (unsigned short*)(ws + 16777216);      // [3072][2048] (wq|wk|wv)
  unsigned short* Wob   = (unsigned short*)(ws + 29360128);      // [2048][2048]
  unsigned short* QKb   = (unsigned short*)(ws + 37748736);      // [4096][2560]
  unsigned short* VTb   = (unsigned short*)(ws + 58720256);      // [512][4096]
  unsigned short* Obuf  = (unsigned short*)(ws + 62914560);      // [4096][2048]
  float* cosT = (float*)(ws + 79691776);                         // [2048][64]
  float* sinT = (float*)(ws + 80216064);

  fused_cast_kernel<<<1024, 256, 0, stream>>>(
      x, wq, wk, wv, wo,
      Xb, Wqkvb,
      Wqkvb + (size_t)D_DIM * D_DIM,          // wk rows at 2048
      Wqkvb + (size_t)NQK * D_DIM,            // wv rows at 2560
      Wob);
  rope_table_kernel<<<512, 256, 0, stream>>>(cosT, sinT);

  // Merged QKV projection: Q,K -> QKb (stride 2560); V -> VTb transposed
  dim3 g1(NTOK / 128, NQKV / 128);            // 32 x 24 = 768 blocks
  gemm_bt_kernel<unsigned short, true><<<g1, 256, 0, stream>>>(
      Xb, Wqkvb, QKb, VTb, NTOK, NQKV, D_DIM);

  norm_rope_kernel<<<(NTOK * (H_HEADS + KV_HEADS)) / 4, 256, 0, stream>>>(QKb, qnw, knw, cosT, sinT);

  attn_kernel<<<dim3(SEQ_L / 128, BATCH * H_HEADS), 256, 0, stream>>>(QKb, VTb, Obuf);

  dim3 g2(NTOK / 128, D_DIM / 128);           // 32 x 16 = 512 blocks
  gemm_bt_kernel<float, false><<<g2, 256, 0, stream>>>(Obuf, Wob, out, nullptr, NTOK, D_DIM, D_DIM);
}